// Round 4
// baseline (108.334 us; speedup 1.0000x reference)
//
#include <hip/hip_runtime.h>

// QDPPMixer, R4: 2 lanes per element (32 elems/wave) + DPP quad-swap reduce.
// R3 lesson: coalesced cooperative gather fixed the concurrency wall (74->34us).
// R4 attacks VALU wave-time: (a) __shfl_xor lowered to ds_bpermute (LDS pipe);
// replace with v_mov_dpp quad_perm [1,0,3,2] (pure VALU). (b) replicated scalar
// work (index calc, M-build, LU, log) amortizes over elements/wave — group=2
// doubles that to 32 elems/wave at identical FMA wave-time and L2 request count.
// Gram accumulates over 4 float4 batches to stay under 128 VGPR.

constexpr int   NA         = 8;
constexpr float Q_MIN      = -10.0f;
constexpr float Q_MAX      = 10.0f;
constexpr float NOISE_COEF = 0.1f;
constexpr float EPS        = 1e-8f;

// swap value with lane^1 within each quad: quad_perm [1,0,3,2] = 0xB1
__device__ __forceinline__ float qswap1(float x) {
    return __builtin_bit_cast(float,
        __builtin_amdgcn_mov_dpp(__builtin_bit_cast(int, x), 0xB1, 0xF, 0xF, true));
}

__global__ __launch_bounds__(256, 4) void qdpp_kernel(
    const float* __restrict__ agent_qs,
    const int*   __restrict__ states,
    const int*   __restrict__ actions,
    const float* __restrict__ noise,
    const float* __restrict__ W,      // (8000, 32) fp32, rows 128B-aligned
    float*       __restrict__ out,
    int bs)
{
    int tid = blockIdx.x * blockDim.x + threadIdx.x;
    int e = tid >> 1;        // element index (2 lanes per element)
    int l = tid & 1;         // lane within pair: covers floats [16l, 16l+16) = one 64B line
    if (e >= bs) return;
    size_t base = (size_t)e * NA;

    // ---- indices (pair-broadcast loads) ----
    int4 s0 = *reinterpret_cast<const int4*>(states + base);
    int4 s1 = *reinterpret_cast<const int4*>(states + base + 4);
    int4 a0 = *reinterpret_cast<const int4*>(actions + base);
    int4 a1 = *reinterpret_cast<const int4*>(actions + base + 4);

    int lb = 16 * l;
    int off[8];
    off[0] = (s0.x * 10 + a0.x        ) * 32 + lb;
    off[1] = (s0.y * 10 + a0.y + 1000 ) * 32 + lb;
    off[2] = (s0.z * 10 + a0.z + 2000 ) * 32 + lb;
    off[3] = (s0.w * 10 + a0.w + 3000 ) * 32 + lb;
    off[4] = (s1.x * 10 + a1.x + 4000 ) * 32 + lb;
    off[5] = (s1.y * 10 + a1.y + 5000 ) * 32 + lb;
    off[6] = (s1.z * 10 + a1.z + 6000 ) * 32 + lb;
    off[7] = (s1.w * 10 + a1.w + 7000 ) * 32 + lb;

    // ---- per-lane partial Gram over this lane's 16 dims, 4 float4 batches ----
    float g[8][8];
    #pragma unroll
    for (int i = 0; i < 8; i++)
        #pragma unroll
        for (int j = i; j < 8; j++)
            g[i][j] = 0.0f;

    #pragma unroll
    for (int c = 0; c < 4; c++) {
        float4 v[8];
        #pragma unroll
        for (int i = 0; i < 8; i++)
            v[i] = *reinterpret_cast<const float4*>(W + off[i] + 4 * c);
        #pragma unroll
        for (int i = 0; i < 8; i++) {
            #pragma unroll
            for (int j = i; j < 8; j++) {
                float acc = g[i][j];
                acc = fmaf(v[i].x, v[j].x, acc);
                acc = fmaf(v[i].y, v[j].y, acc);
                acc = fmaf(v[i].z, v[j].z, acc);
                acc = fmaf(v[i].w, v[j].w, acc);
                g[i][j] = acc;
            }
        }
    }

    // ---- reduce across the lane pair: one DPP quad-swap round ----
    #pragma unroll
    for (int i = 0; i < 8; i++)
        #pragma unroll
        for (int j = i; j < 8; j++)
            g[i][j] += qswap1(g[i][j]);

    // ---- Q-sum with clip (pair-broadcast) ----
    float4 qa = *reinterpret_cast<const float4*>(agent_qs + base);
    float4 qb = *reinterpret_cast<const float4*>(agent_qs + base + 4);
    float qsum = fminf(fmaxf(qa.x, Q_MIN), Q_MAX) + fminf(fmaxf(qa.y, Q_MIN), Q_MAX)
               + fminf(fmaxf(qa.z, Q_MIN), Q_MAX) + fminf(fmaxf(qa.w, Q_MIN), Q_MAX)
               + fminf(fmaxf(qb.x, Q_MIN), Q_MAX) + fminf(fmaxf(qb.y, Q_MIN), Q_MAX)
               + fminf(fmaxf(qb.z, Q_MIN), Q_MAX) + fminf(fmaxf(qb.w, Q_MIN), Q_MAX);

    // ---- normalization scales from diagonal (rows are ~unit: g[i][i]>0) ----
    float inv[8];
    #pragma unroll
    for (int i = 0; i < 8; i++)
        inv[i] = rsqrtf(fmaxf(g[i][i], 1e-24f));

    // ---- noise (pair-broadcast) ----
    float4 n0 = *reinterpret_cast<const float4*>(noise + base);
    float4 n1 = *reinterpret_cast<const float4*>(noise + base + 4);
    float nz[8] = {n0.x, n0.y, n0.z, n0.w, n1.x, n1.y, n1.z, n1.w};

    // ---- M = relu(normalized Gram + diag(noise*coef)) + eps ----
    float m[8][8];
    #pragma unroll
    for (int i = 0; i < 8; i++) {
        #pragma unroll
        for (int j = 0; j < 8; j++) {
            float gij = (j >= i) ? g[i][j] : g[j][i];   // compile-time select
            float val = gij * inv[i] * inv[j];
            if (i == j) val += nz[i] * NOISE_COEF;
            m[i][j] = fmaxf(val, 0.0f) + EPS;
        }
    }

    // ---- det via unrolled no-pivot LU (diag-dominant in practice);
    //      v_rcp_f32 (~1e-7 rel) is plenty for the 0.255 threshold ----
    float det = 1.0f;
    #pragma unroll
    for (int k = 0; k < 8; k++) {
        float p = m[k][k];
        det *= p;
        float ip = __builtin_amdgcn_rcpf(p);
        #pragma unroll
        for (int i = k + 1; i < 8; i++) {
            float f = m[i][k] * ip;
            #pragma unroll
            for (int j = k + 1; j < 8; j++)
                m[i][j] = fmaf(-f, m[k][j], m[i][j]);
        }
    }

    if (l == 0)
        out[e] = qsum + __logf(det + EPS);
}

extern "C" void kernel_launch(void* const* d_in, const int* in_sizes, int n_in,
                              void* d_out, int out_size, void* d_ws, size_t ws_size,
                              hipStream_t stream) {
    const float* agent_qs = (const float*)d_in[0];
    const int*   states   = (const int*)d_in[1];
    const int*   actions  = (const int*)d_in[2];
    const float* noise    = (const float*)d_in[3];
    const float* W        = (const float*)d_in[4];
    float*       out      = (float*)d_out;

    int bs = in_sizes[0] / NA;            // 262144
    const int block = 256;
    long long total = (long long)bs * 2;  // 2 lanes per element
    int grid = (int)((total + block - 1) / block);
    qdpp_kernel<<<grid, block, 0, stream>>>(agent_qs, states, actions, noise, W, out, bs);
}

// Round 5
// 97.059 us; speedup vs baseline: 1.1162x; 1.1162x over previous
//
#include <hip/hip_runtime.h>

// QDPPMixer, R5: G=4 cooperative gather (R3 structure: each gather instr touches
// 16 lines, 4-way lane-shared, each line fetched once) + DPP quad-butterfly
// reduce (no LDS pipe) + algebraic normalize elimination:
//   relu(a*x) = a*relu(x) for a>0, and normalized diag == 1 exactly, so
//   M = D * Atil * D,  Atil_ij = relu(g_ij) (i!=j),  Atil_ii = g_ii*(1+0.1*nz_i+eps)
//   => logdet M = log(det(Atil) / prod(g_ii))   -- no rsqrt, no normalize muls,
//   one log total. Off-diag +1e-8 dropped (perturbs logdet by ~1e-3 << 0.255).

constexpr int   NA         = 8;
constexpr float Q_MIN      = -10.0f;
constexpr float Q_MAX      = 10.0f;
constexpr float NOISE_COEF = 0.1f;
constexpr float EPS        = 1e-8f;

// add value from lane^1 within quad: quad_perm [1,0,3,2] = 0xB1
__device__ __forceinline__ float qadd1(float x) {
    return x + __builtin_bit_cast(float,
        __builtin_amdgcn_mov_dpp(__builtin_bit_cast(int, x), 0xB1, 0xF, 0xF, true));
}
// add value from lane^2 within quad: quad_perm [2,3,0,1] = 0x4E
__device__ __forceinline__ float qadd2(float x) {
    return x + __builtin_bit_cast(float,
        __builtin_amdgcn_mov_dpp(__builtin_bit_cast(int, x), 0x4E, 0xF, 0xF, true));
}

__global__ __launch_bounds__(256, 4) void qdpp_kernel(
    const float* __restrict__ agent_qs,
    const int*   __restrict__ states,
    const int*   __restrict__ actions,
    const float* __restrict__ noise,
    const float* __restrict__ W,      // (8000, 32) fp32, rows 128B-aligned
    float*       __restrict__ out,
    int bs)
{
    int tid = blockIdx.x * blockDim.x + threadIdx.x;
    int e = tid >> 2;        // element index (4 lanes per element)
    int l = tid & 3;         // lane in quad: covers floats [4l,4l+4) and [16+4l,16+4l+4)
    if (e >= bs) return;
    size_t base = (size_t)e * NA;

    // ---- indices (quad-broadcast loads) ----
    int4 s0 = *reinterpret_cast<const int4*>(states + base);
    int4 s1 = *reinterpret_cast<const int4*>(states + base + 4);
    int4 a0 = *reinterpret_cast<const int4*>(actions + base);
    int4 a1 = *reinterpret_cast<const int4*>(actions + base + 4);

    int lb = 4 * l;
    int off[8];
    off[0] = (s0.x * 10 + a0.x        ) * 32 + lb;
    off[1] = (s0.y * 10 + a0.y + 1000 ) * 32 + lb;
    off[2] = (s0.z * 10 + a0.z + 2000 ) * 32 + lb;
    off[3] = (s0.w * 10 + a0.w + 3000 ) * 32 + lb;
    off[4] = (s1.x * 10 + a1.x + 4000 ) * 32 + lb;
    off[5] = (s1.y * 10 + a1.y + 5000 ) * 32 + lb;
    off[6] = (s1.z * 10 + a1.z + 6000 ) * 32 + lb;
    off[7] = (s1.w * 10 + a1.w + 7000 ) * 32 + lb;

    // ---- all 16 gather loads issued up-front (each instr: 16 lines, 4-way shared) ----
    float4 va[8], vb[8];
    #pragma unroll
    for (int i = 0; i < 8; i++)
        va[i] = *reinterpret_cast<const float4*>(W + off[i]);
    #pragma unroll
    for (int i = 0; i < 8; i++)
        vb[i] = *reinterpret_cast<const float4*>(W + off[i] + 16);

    // ---- streaming loads issued while gathers are in flight ----
    float4 qa = *reinterpret_cast<const float4*>(agent_qs + base);
    float4 qb = *reinterpret_cast<const float4*>(agent_qs + base + 4);
    float4 n0 = *reinterpret_cast<const float4*>(noise + base);
    float4 n1 = *reinterpret_cast<const float4*>(noise + base + 4);

    // ---- per-lane partial Gram (this lane's 8 of 32 dims), upper triangle ----
    float g[8][8];
    #pragma unroll
    for (int i = 0; i < 8; i++) {
        #pragma unroll
        for (int j = i; j < 8; j++) {
            float acc;
            acc = va[i].x * va[j].x;
            acc = fmaf(va[i].y, va[j].y, acc);
            acc = fmaf(va[i].z, va[j].z, acc);
            acc = fmaf(va[i].w, va[j].w, acc);
            acc = fmaf(vb[i].x, vb[j].x, acc);
            acc = fmaf(vb[i].y, vb[j].y, acc);
            acc = fmaf(vb[i].z, vb[j].z, acc);
            acc = fmaf(vb[i].w, vb[j].w, acc);
            g[i][j] = acc;
        }
    }

    // ---- quad butterfly reduce, pure VALU DPP (no LDS) ----
    #pragma unroll
    for (int i = 0; i < 8; i++)
        #pragma unroll
        for (int j = i; j < 8; j++)
            g[i][j] = qadd2(qadd1(g[i][j]));

    // ---- Q-sum with clip (v_med3 clamps) ----
    float qsum = fminf(fmaxf(qa.x, Q_MIN), Q_MAX) + fminf(fmaxf(qa.y, Q_MIN), Q_MAX)
               + fminf(fmaxf(qa.z, Q_MIN), Q_MAX) + fminf(fmaxf(qa.w, Q_MIN), Q_MAX)
               + fminf(fmaxf(qb.x, Q_MIN), Q_MAX) + fminf(fmaxf(qb.y, Q_MIN), Q_MAX)
               + fminf(fmaxf(qb.z, Q_MIN), Q_MAX) + fminf(fmaxf(qb.w, Q_MIN), Q_MAX);

    float nz[8] = {n0.x, n0.y, n0.z, n0.w, n1.x, n1.y, n1.z, n1.w};

    // ---- Atil: off-diag = relu(raw gram), diag = g_ii*(1 + 0.1*nz + eps) ----
    float m[8][8];
    float pgii = 1.0f;
    #pragma unroll
    for (int i = 0; i < 8; i++) {
        pgii *= g[i][i];
        #pragma unroll
        for (int j = 0; j < 8; j++) {
            if (i == j) {
                m[i][i] = g[i][i] * fmaf(NOISE_COEF, nz[i], 1.0f + EPS);
            } else {
                float gij = (j > i) ? g[i][j] : g[j][i];   // compile-time select
                m[i][j] = fmaxf(gij, 0.0f);
            }
        }
    }

    // ---- det via unrolled no-pivot LU (diag-dominant in practice) ----
    float det = 1.0f;
    #pragma unroll
    for (int k = 0; k < 8; k++) {
        float p = m[k][k];
        det *= p;
        float ip = __builtin_amdgcn_rcpf(p);
        #pragma unroll
        for (int i = k + 1; i < 8; i++) {
            float f = m[i][k] * ip;
            #pragma unroll
            for (int j = k + 1; j < 8; j++)
                m[i][j] = fmaf(-f, m[k][j], m[i][j]);
        }
    }

    // det(M) = det(Atil) / prod(g_ii); out = qsum + log(det(M) + 1e-8)
    float detM = det * __builtin_amdgcn_rcpf(pgii);
    if (l == 0)
        out[e] = qsum + __logf(detM + EPS);
}

extern "C" void kernel_launch(void* const* d_in, const int* in_sizes, int n_in,
                              void* d_out, int out_size, void* d_ws, size_t ws_size,
                              hipStream_t stream) {
    const float* agent_qs = (const float*)d_in[0];
    const int*   states   = (const int*)d_in[1];
    const int*   actions  = (const int*)d_in[2];
    const float* noise    = (const float*)d_in[3];
    const float* W        = (const float*)d_in[4];
    float*       out      = (float*)d_out;

    int bs = in_sizes[0] / NA;            // 262144
    const int block = 256;
    long long total = (long long)bs * 4;  // 4 lanes per element
    int grid = (int)((total + block - 1) / block);
    qdpp_kernel<<<grid, block, 0, stream>>>(agent_qs, states, actions, noise, W, out, bs);
}